// Round 10
// baseline (485.395 us; speedup 1.0000x reference)
//
#include <hip/hip_runtime.h>
#include <hip/hip_fp8.h>
#include <math.h>

constexpr int NN = 100000;   // nodes
constexpr int NE = 1600000;  // edges
constexpr int H  = 128;      // feat/hidden
constexpr int NG = 100;      // graphs
constexpr int NC = 10;       // classes
constexpr int NB = 391;      // CSR buckets (dst >> 8), 256 nodes each
constexpr int CAP = 4608;    // per-bucket staging capacity (mean 4096 + 8 sigma)
constexpr int NSLOT = 128;   // BN stats partial slots per layer (~8 concurrent writers/addr)
constexpr int B1B = 196;     // bucket1 blocks = ceil(NE/8192)
constexpr int GEMM_BLOCKS = 1563;  // 6252 waves -> exactly one 16-row tile per wave (churn)

typedef _Float16 half8 __attribute__((ext_vector_type(8)));
typedef _Float16 half4 __attribute__((ext_vector_type(4)));
typedef _Float16 h2v   __attribute__((ext_vector_type(2)));
typedef float    f32x4 __attribute__((ext_vector_type(4)));
typedef float    f32x2 __attribute__((ext_vector_type(2)));

// ---- fp8 e4m3 (OCP) helpers ----
static __device__ __forceinline__ unsigned char ftofp8(float f) {
#if __has_builtin(__builtin_amdgcn_cvt_pk_fp8_f32)
    int r = __builtin_amdgcn_cvt_pk_fp8_f32(f, f, 0, false);
    return (unsigned char)(r & 0xff);
#else
    __hip_fp8_e4m3 v(f);
    unsigned char b; __builtin_memcpy(&b, &v, 1); return b;
#endif
}

// pack 4 floats into 4 fp8 bytes of one u32 (2 instrs)
static __device__ __forceinline__ unsigned int pk4fp8(float a, float b, float c, float d) {
#if __has_builtin(__builtin_amdgcn_cvt_pk_fp8_f32)
    int w = __builtin_amdgcn_cvt_pk_fp8_f32(a, b, 0, false);
    w = __builtin_amdgcn_cvt_pk_fp8_f32(c, d, w, true);
    return (unsigned int)w;
#else
    return (unsigned int)ftofp8(a) | ((unsigned int)ftofp8(b) << 8) |
           ((unsigned int)ftofp8(c) << 16) | ((unsigned int)ftofp8(d) << 24);
#endif
}

template <bool HI>
static __device__ __forceinline__ f32x2 fp8x2tof(unsigned int u) {
#if __has_builtin(__builtin_amdgcn_cvt_pk_f32_fp8)
    return __builtin_amdgcn_cvt_pk_f32_fp8(u, HI);  // HI is a constant here
#else
    f32x2 r;
    #pragma unroll
    for (int i = 0; i < 2; i++) {
        unsigned char b = (u >> (8 * (i + (HI ? 2 : 0)))) & 0xff;
        __hip_fp8_e4m3 v; __builtin_memcpy(&v, &b, 1); r[i] = (float)v;
    }
    return r;
#endif
}

// packed f16 relu
static __device__ __forceinline__ half8 h8_relu(half8 v) {
    half8 z = {};
#if __has_builtin(__builtin_elementwise_max)
    return __builtin_elementwise_max(v, z);
#else
    half8 o;
    #pragma unroll
    for (int i = 0; i < 8; i++) o[i] = v[i] > (_Float16)0 ? v[i] : (_Float16)0;
    return o;
#endif
}

// ---------------- CSR pass 1 (blocks 0..195): bin edges into 391 dst buckets ----------------
// blocks 196..388: W -> Wt (transposed f16, permuted rows) + gstart binary search (merged prepw3)
__global__ __launch_bounds__(256) void k_bucket1(const int* __restrict__ src,
                                                 const int* __restrict__ dst,
                                                 int* __restrict__ bcnt,
                                                 unsigned int* __restrict__ staging,
                                                 const float* __restrict__ W0,
                                                 const float* __restrict__ W1,
                                                 const float* __restrict__ W2,
                                                 _Float16* __restrict__ Wt,
                                                 const int* __restrict__ batch,
                                                 int* __restrict__ gstart) {
    int tid = threadIdx.x;
    if (blockIdx.x >= B1B) {
        int pb = blockIdx.x - B1B;          // 0..192
        if (pb == 192) {
            int g = tid;
            if (g > NG) return;
            if (g == NG) { gstart[g] = NN; return; }
            int lo = 0, hi = NN;
            while (lo < hi) { int mid = (lo + hi) >> 1; if (batch[mid] < g) lo = mid + 1; else hi = mid; }
            gstart[g] = lo;
            return;
        }
        int gi = pb * 256 + tid;            // 3 * 16384
        int l = gi >> 14, idx = gi & 16383;
        const float* W = (l == 0) ? W0 : (l == 1) ? W1 : W2;
        int n = idx >> 7, k = idx & 127;
        int c = ((n & 15) << 3) | (n >> 4);
        Wt[gi - idx + (n << 7) + k] = (_Float16)W[k * 128 + c];
        return;
    }
    __shared__ int hist[NB];
    __shared__ int base[NB];
    int chunk0 = blockIdx.x * 8192;
    bool full = (chunk0 + 8192 <= NE);
    for (int i = tid; i < NB; i += 256) hist[i] = 0;
    __syncthreads();
    if (full) {
        for (int i = tid * 4; i < 8192; i += 1024) {
            int4 d4 = *(const int4*)&dst[chunk0 + i];
            atomicAdd(&hist[d4.x >> 8], 1);
            atomicAdd(&hist[d4.y >> 8], 1);
            atomicAdd(&hist[d4.z >> 8], 1);
            atomicAdd(&hist[d4.w >> 8], 1);
        }
    } else {
        for (int i = tid; i < 8192; i += 256) {
            int e = chunk0 + i;
            if (e < NE) atomicAdd(&hist[dst[e] >> 8], 1);
        }
    }
    __syncthreads();
    for (int i = tid; i < NB; i += 256) {
        base[i] = atomicAdd(&bcnt[i], hist[i]);
        hist[i] = 0;
    }
    __syncthreads();
    if (full) {
        for (int i = tid * 4; i < 8192; i += 1024) {
            int4 d4 = *(const int4*)&dst[chunk0 + i];
            int4 s4 = *(const int4*)&src[chunk0 + i];
            #pragma unroll
            for (int k = 0; k < 4; k++) {
                int d = (k == 0) ? d4.x : (k == 1) ? d4.y : (k == 2) ? d4.z : d4.w;
                int s = (k == 0) ? s4.x : (k == 1) ? s4.y : (k == 2) ? s4.z : s4.w;
                int bk = d >> 8;
                int off = base[bk] + atomicAdd(&hist[bk], 1);
                if (off < CAP)
                    staging[(size_t)bk * CAP + off] = ((unsigned)s << 8) | (unsigned)(d & 255);
            }
        }
    } else {
        for (int i = tid; i < 8192; i += 256) {
            int e = chunk0 + i;
            if (e < NE) {
                int d = dst[e];
                int bk = d >> 8;
                int off = base[bk] + atomicAdd(&hist[bk], 1);
                if (off < CAP)
                    staging[(size_t)bk * CAP + off] = ((unsigned)src[e] << 8) | (unsigned)(d & 255);
            }
        }
    }
}

// ---------------- CSR pass 2: 391 blocks, 256 nodes/block, 1 node/thread ----------------
__global__ __launch_bounds__(256) void k_bucket2(const unsigned int* __restrict__ staging,
                                                 const int* __restrict__ bcnt,
                                                 int* __restrict__ rowptr,
                                                 float* __restrict__ dis,
                                                 int* __restrict__ col) {
    __shared__ int degl[256];
    __shared__ int cur[256];
    __shared__ int tsum[256];
    __shared__ int sbc[NB];
    __shared__ int sbase_s;
    int b = blockIdx.x, tid = threadIdx.x;
    for (int i = tid; i < NB; i += 256) sbc[i] = bcnt[i];
    degl[tid] = 0;
    __syncthreads();
    if (tid == 0) { int r = 0; for (int i = 0; i < b; i++) r += sbc[i]; sbase_s = r; }
    __syncthreads();
    int cnt = sbc[b]; if (cnt > CAP) cnt = CAP;
    int base = sbase_s;
    const unsigned int* st = staging + (size_t)b * CAP;
    for (int i = tid; i < cnt; i += 256) atomicAdd(&degl[st[i] & 255], 1);
    __syncthreads();
    int d = degl[tid];
    tsum[tid] = d;
    __syncthreads();
    for (int off = 1; off < 256; off <<= 1) {
        int t = (tid >= off) ? tsum[tid - off] : 0;
        __syncthreads();
        tsum[tid] += t;
        __syncthreads();
    }
    int excl = tsum[tid] - d;
    int node = b * 256 + tid;
    if (node <= NN) rowptr[node] = base + excl;
    if (node < NN) {
        cur[tid] = excl;
        dis[node] = rsqrtf((float)d + 1.0f);
    }
    __syncthreads();
    for (int i = tid; i < cnt; i += 256) {
        unsigned int e = st[i];
        int pos = atomicAdd(&cur[e & 255], 1);
        col[base + pos] = (int)(e >> 8);
    }
}

// ---------------- MFMA GEMM v6: NO LDS W staging -- B-fragments direct from L2-hot Wt ----------------
// Wt is 32KB and read by every block: L2-resident. Dropping the 34.8KB LDS stage removes
// 9 sequential staging rounds + barrier from every (now single-tile) block's critical path
// and lifts the 4-blocks/CU LDS occupancy cap. B addresses are base + compile-time offsets.
__global__ __launch_bounds__(256) void k_gemm(const float* __restrict__ Xf,
                                              const _Float16* __restrict__ Xh,
                                              const float* __restrict__ sp,
                                              const float* __restrict__ gamma,
                                              const float* __restrict__ beta,
                                              const _Float16* __restrict__ Wt,
                                              const float* __restrict__ dis,
                                              unsigned char* __restrict__ Y) {
    __shared__ _Float16 ssh[256];
    __shared__ float sums[256];
    int tid = threadIdx.x;
    if (Xh) {
        float a = 0.f;
        #pragma unroll 4
        for (int i = 0; i < NSLOT; i++) a += sp[i * 256 + tid];
        sums[tid] = a;
        __syncthreads();
        if (tid < 128) {
            float mean = sums[tid] * (1.0f / NN);
            float var  = sums[128 + tid] * (1.0f / NN) - mean * mean;
            float sc   = gamma[tid] * rsqrtf(var + 1e-5f);
            ssh[tid] = (_Float16)sc;
            ssh[128 + tid] = (_Float16)(beta[tid] - mean * sc);
        }
        __syncthreads();
    }

    int lane = tid & 63;
    int m = lane & 15;
    int quad = lane >> 4;
    const int NT = (NN + 15) / 16;          // 6250 tiles

    int t = blockIdx.x * 4 + (tid >> 6);    // one tile per wave
    if (t < NT) {
        int row = t * 16 + m;
        bool ok = row < NN;
        half8 afrag[4];
        if (Xh) {
            #pragma unroll
            for (int kc = 0; kc < 4; kc++) {
                int k0 = kc * 32 + quad * 8;
                half8 hv = {};
                if (ok) hv = *(const half8*)&Xh[(size_t)row * H + k0];
                half8 scv = *(const half8*)&ssh[k0];
                half8 shv = *(const half8*)&ssh[k0 + 128];
                afrag[kc] = h8_relu(hv * scv + shv);
            }
        } else {
            #pragma unroll
            for (int kc = 0; kc < 4; kc++) {
                int k0 = kc * 32 + quad * 8;
                float4 v0 = make_float4(0.f, 0.f, 0.f, 0.f);
                float4 v1 = make_float4(0.f, 0.f, 0.f, 0.f);
                if (ok) {
                    v0 = *(const float4*)&Xf[(size_t)row * H + k0];
                    v1 = *(const float4*)&Xf[(size_t)row * H + k0 + 4];
                }
                half8 o = {(_Float16)v0.x, (_Float16)v0.y, (_Float16)v0.z, (_Float16)v0.w,
                           (_Float16)v1.x, (_Float16)v1.y, (_Float16)v1.z, (_Float16)v1.w};
                afrag[kc] = o;
            }
        }

        // B-fragments direct from global Wt (row = nt*16+m, col = kc*32+quad*8); L2-hit.
        const _Float16* wb = Wt + (size_t)m * H + quad * 8;
        f32x4 acc[8];
        #pragma unroll
        for (int nt = 0; nt < 8; nt++) acc[nt] = (f32x4){0.f, 0.f, 0.f, 0.f};
        #pragma unroll
        for (int kc = 0; kc < 4; kc++) {
            #pragma unroll
            for (int nt = 0; nt < 8; nt++) {
                half8 b = *(const half8*)&wb[nt * 16 * H + kc * 32];
                acc[nt] = __builtin_amdgcn_mfma_f32_16x16x32_f16(afrag[kc], b, acc[nt], 0, 0, 0);
            }
        }

        #pragma unroll
        for (int r = 0; r < 4; r++) {
            int gr = t * 16 + quad * 4 + r;
            if (gr < NN) {
                float dv = dis[gr];
                unsigned int lo = pk4fp8(acc[0][r] * dv, acc[1][r] * dv,
                                         acc[2][r] * dv, acc[3][r] * dv);
                unsigned int hi = pk4fp8(acc[4][r] * dv, acc[5][r] * dv,
                                         acc[6][r] * dv, acc[7][r] * dv);
                uint2 pk = make_uint2(lo, hi);
                *(uint2*)&Y[(size_t)gr * H + m * 8] = pk;
            }
        }
    }
}

// ---------------- gather aggregate + BN stats partials ----------------
// Round-0-proven latency structure: ONE node per wave, short-lived waves, 8 edge
// substreams x 8 feature-lanes, uint4 gathers, 2-deep unroll (16 outstanding loads).
// Epilogue: reduce-scatter butterfly, LDS flush + 256 sp atomics per 4-node block.
// NO device fence (round-3: per-block __threadfence = 34x regression).
// NSLOT=128: ~8 concurrent atomic writers per sp address (32 caused +5us, round 7).
__global__ __launch_bounds__(256) void k_agg(const unsigned char* __restrict__ hs,
                                             const int* __restrict__ rowptr,
                                             const int* __restrict__ col,
                                             const float* __restrict__ dis,
                                             const float* __restrict__ bias,
                                             _Float16* __restrict__ out,
                                             float* __restrict__ sp) {
    int wv = threadIdx.x >> 6;            // 0..3
    int lane = threadIdx.x & 63;
    int fl = lane & 7;     // feature slice: feats 16*fl .. 16*fl+15
    int sub = lane >> 3;   // edge sub-stream 0..7
    int b0 = sub & 1, b1 = (sub >> 1) & 1, b2 = (sub >> 2) & 1;
    const uint4* h16 = (const uint4*)hs;  // 8 uint4 per 128B row
    int node = blockIdx.x * 4 + wv;       // grid exactly covers NN
    int beg = rowptr[node], end = rowptr[node + 1];
    float dd = dis[node];
    // after reduce-scatter this lane owns feature pair p = fl*16 + sub*2
    float2 bb = *(const float2*)&bias[fl * 16 + sub * 2];

    f32x2 acc2[8];
    #pragma unroll
    for (int k = 0; k < 8; k++) acc2[k] = (f32x2){0.f, 0.f};

    #define ACCUM(W) { \
        acc2[0] += fp8x2tof<false>((W).x); acc2[1] += fp8x2tof<true>((W).x); \
        acc2[2] += fp8x2tof<false>((W).y); acc2[3] += fp8x2tof<true>((W).y); \
        acc2[4] += fp8x2tof<false>((W).z); acc2[5] += fp8x2tof<true>((W).z); \
        acc2[6] += fp8x2tof<false>((W).w); acc2[7] += fp8x2tof<true>((W).w); }
    #define SHFL2(d, s, m) { (d)[0] = __shfl_xor((s)[0], (m), 64); (d)[1] = __shfl_xor((s)[1], (m), 64); }

    if (sub == 0) {                               // self-loop term
        uint4 w = h16[(size_t)node * 8 + fl];
        ACCUM(w)
    }
    int j = beg + sub;
    for (; j + 8 < end; j += 16) {
        int c0 = col[j], c1 = col[j + 8];
        uint4 w0 = h16[(size_t)c0 * 8 + fl];
        uint4 w1 = h16[(size_t)c1 * 8 + fl];
        ACCUM(w0) ACCUM(w1)
    }
    for (; j < end; j += 8) {
        uint4 w = h16[(size_t)col[j] * 8 + fl];
        ACCUM(w)
    }
    #undef ACCUM

    // ---- reduce-scatter butterfly: lane (fl,sub) ends with sum for pair t = sub ----
    f32x2 n0, n1, n2, n3, t, r;
    t = b0 ? acc2[0] : acc2[1]; SHFL2(r, t, 8); n0 = (b0 ? acc2[1] : acc2[0]) + r;
    t = b0 ? acc2[2] : acc2[3]; SHFL2(r, t, 8); n1 = (b0 ? acc2[3] : acc2[2]) + r;
    t = b0 ? acc2[4] : acc2[5]; SHFL2(r, t, 8); n2 = (b0 ? acc2[5] : acc2[4]) + r;
    t = b0 ? acc2[6] : acc2[7]; SHFL2(r, t, 8); n3 = (b0 ? acc2[7] : acc2[6]) + r;
    f32x2 m0, m1;
    t = b1 ? n0 : n1; SHFL2(r, t, 16); m0 = (b1 ? n1 : n0) + r;
    t = b1 ? n2 : n3; SHFL2(r, t, 16); m1 = (b1 ? n3 : n2) + r;
    t = b2 ? m0 : m1; SHFL2(r, t, 32); f32x2 fin = (b2 ? m1 : m0) + r;
    #undef SHFL2

    float o0 = fin[0] * dd + bb.x;
    float o1 = fin[1] * dd + bb.y;
    h2v ov = { (_Float16)o0, (_Float16)o1 };
    *(h2v*)&out[(size_t)node * H + fl * 16 + sub * 2] = ov;   // coalesced 256B row / wave

    __shared__ float lsum[4][128];
    __shared__ float lsq[4][128];
    {
        int p = fl * 16 + sub * 2;
        *(float2*)&lsum[wv][p] = make_float2(o0, o1);
        *(float2*)&lsq[wv][p]  = make_float2(o0 * o0, o1 * o1);
    }
    __syncthreads();
    int c = threadIdx.x & 127;
    int which = threadIdx.x >> 7;  // 0 = sum, 1 = sumsq
    float v = 0.f;
    #pragma unroll
    for (int w = 0; w < 4; w++) v += which ? lsq[w][c] : lsum[w][c];
    atomicAdd(&sp[(blockIdx.x & (NSLOT - 1)) * 256 + which * 128 + c], v);
}

// ---------------- fused BN-stats reduce + mean pool (BN+ReLU) + MLP head + log_softmax ----------------
__global__ __launch_bounds__(1024) void k_poolhead(const _Float16* __restrict__ x,
                                                   const float* __restrict__ sp,
                                                   const float* __restrict__ gamma,
                                                   const float* __restrict__ beta,
                                                   const int* __restrict__ gstart,
                                                   const float* __restrict__ w1, const float* __restrict__ b1,
                                                   const float* __restrict__ w2, const float* __restrict__ b2,
                                                   float* __restrict__ out) {
    __shared__ float part[4][256];
    __shared__ float ssl[256];
    int t = threadIdx.x;
    {
        int c = t & 255, g4 = t >> 8;     // 4 groups x NSLOT/4 slots
        float a = 0.f;
        for (int i = g4 * (NSLOT / 4); i < (g4 + 1) * (NSLOT / 4); i++) a += sp[i * 256 + c];
        part[g4][c] = a;
    }
    __syncthreads();
    if (t < 256) part[0][t] = part[0][t] + part[1][t] + part[2][t] + part[3][t];
    __syncthreads();
    if (t < 128) {
        float mean = part[0][t] * (1.0f / NN);
        float var  = part[0][128 + t] * (1.0f / NN) - mean * mean;
        float sc   = gamma[t] * rsqrtf(var + 1e-5f);
        ssl[t] = sc;
        ssl[128 + t] = beta[t] - mean * sc;
    }
    __syncthreads();

    int g = blockIdx.x;
    int beg = gstart[g], end = gstart[g + 1];
    int lane = t & 31;
    int walker = t >> 5;   // 0..31
    const half4* x4 = (const half4*)x;
    float4 sc4 = ((const float4*)ssl)[lane];
    float4 sh4 = ((const float4*)(ssl + 128))[lane];
    float4 acc = make_float4(0.f, 0.f, 0.f, 0.f);
    for (int r = beg + walker; r < end; r += 32) {
        half4 v = x4[(size_t)r * 32 + lane];
        acc.x += fmaxf((float)v.x * sc4.x + sh4.x, 0.f);
        acc.y += fmaxf((float)v.y * sc4.y + sh4.y, 0.f);
        acc.z += fmaxf((float)v.z * sc4.z + sh4.z, 0.f);
        acc.w += fmaxf((float)v.w * sc4.w + sh4.w, 0.f);
    }
    __shared__ float4 red[1024];
    __shared__ float p[H], hh[H], lg[NC], lsred;
    red[t] = acc;
    __syncthreads();
    if (t < 32) {
        float4 s = red[t];
        for (int w = 1; w < 32; w++) {
            float4 v = red[w * 32 + t];
            s.x += v.x; s.y += v.y; s.z += v.z; s.w += v.w;
        }
        float inv = 1.0f / fmaxf((float)(end - beg), 1.0f);
        ((float4*)p)[t] = make_float4(s.x * inv, s.y * inv, s.z * inv, s.w * inv);
    }
    __syncthreads();
    int f = t;
    if (f < H) {
        float a = b1[f];
        for (int k = 0; k < H; k++) a += p[k] * w1[k * H + f];
        hh[f] = a > 0.f ? a : 0.f;
    }
    __syncthreads();
    if (f < NC) {
        float l = b2[f];
        for (int k = 0; k < H; k++) l += hh[k] * w2[k * NC + f];
        lg[f] = l;
    }
    __syncthreads();
    if (f == 0) {
        float m = lg[0];
        for (int c = 1; c < NC; c++) m = m > lg[c] ? m : lg[c];
        float s = 0.f;
        for (int c = 0; c < NC; c++) s += expf(lg[c] - m);
        lsred = m + logf(s);
    }
    __syncthreads();
    if (f < NC) out[g * NC + f] = lg[f] - lsred;
}

extern "C" void kernel_launch(void* const* d_in, const int* in_sizes, int n_in,
                              void* d_out, int out_size, void* d_ws, size_t ws_size,
                              hipStream_t stream) {
    const float* x     = (const float*)d_in[0];
    const int*   ei    = (const int*)d_in[1];
    const int*   srcp  = ei;
    const int*   dstp  = ei + NE;
    const int*   batch = (const int*)d_in[2];
    const float* W[3]  = {(const float*)d_in[3],  (const float*)d_in[7],  (const float*)d_in[11]};
    const float* b[3]  = {(const float*)d_in[4],  (const float*)d_in[8],  (const float*)d_in[12]};
    const float* gm[3] = {(const float*)d_in[5],  (const float*)d_in[9],  (const float*)d_in[13]};
    const float* bt[3] = {(const float*)d_in[6],  (const float*)d_in[10], (const float*)d_in[14]};
    const float* w1 = (const float*)d_in[15];
    const float* b1 = (const float*)d_in[16];
    const float* w2 = (const float*)d_in[17];
    const float* b2 = (const float*)d_in[18];
    float* out = (float*)d_out;

    float* ws        = (float*)d_ws;
    float* dis       = ws;                          // 100000
    int*   rowptr    = (int*)(ws + 100000);         // 100001 (pad 100004)
    int*   gstart    = (int*)(ws + 200004);         // 101 (pad 104)
    int*   bcnt      = (int*)(ws + 200108);         // 391 (pad 512)
    float* sp        = ws + 200620;                 // 3 layers x NSLOT*256 = 98304
    _Float16* wt     = (_Float16*)(ws + 298924);    // 3*16384 halves = 24576 floats
    int*   col       = (int*)(ws + 323500);         // NE
    unsigned int* staging = (unsigned int*)(ws + 1923500);  // NB*CAP = 1801728
    _Float16* aggh   = (_Float16*)(ws + 3725228);   // NN*H f16 = 6400000 floats
    unsigned char* hb = (unsigned char*)(ws + 10125228);  // NN*H fp8

    // one memset covers bcnt (512) + all 3 layers' sp partials
    (void)hipMemsetAsync(bcnt, 0, (512 + 3 * NSLOT * 256) * sizeof(float), stream);
    k_bucket1<<<B1B + 193, 256, 0, stream>>>(srcp, dstp, bcnt, staging,
                                             W[0], W[1], W[2], wt, batch, gstart);
    k_bucket2<<<NB, 256, 0, stream>>>(staging, bcnt, rowptr, dis, col);

    for (int l = 0; l < 3; l++) {
        k_gemm<<<GEMM_BLOCKS, 256, 0, stream>>>(
            l == 0 ? x : nullptr,
            l == 0 ? nullptr : aggh,
            l == 0 ? nullptr : sp + (l - 1) * NSLOT * 256,
            l == 0 ? nullptr : gm[l - 1],
            l == 0 ? nullptr : bt[l - 1],
            wt + l * 16384, dis, hb);
        k_agg<<<NN / 4, 256, 0, stream>>>(hb, rowptr, col, dis, b[l], aggh,
                                          sp + l * NSLOT * 256);
    }

    k_poolhead<<<NG, 1024, 0, stream>>>(aggh, sp + 2 * NSLOT * 256, gm[2], bt[2],
                                        gstart, w1, b1, w2, b2, out);
}

// Round 11
// 411.734 us; speedup vs baseline: 1.1789x; 1.1789x over previous
//
#include <hip/hip_runtime.h>
#include <hip/hip_fp8.h>
#include <math.h>

constexpr int NN = 100000;   // nodes
constexpr int NE = 1600000;  // edges
constexpr int H  = 128;      // feat/hidden
constexpr int NG = 100;      // graphs
constexpr int NC = 10;       // classes
constexpr int NB = 391;      // CSR buckets (dst >> 8), 256 nodes each
constexpr int CAP = 4608;    // per-bucket staging capacity (mean 4096 + 8 sigma)
constexpr int NSLOT = 128;   // BN stats partial slots per layer (~8 concurrent writers/addr)
constexpr int B1B = 196;     // bucket1 blocks = ceil(NE/8192)
constexpr int GEMM_BLOCKS = 1563;  // 6252 waves -> exactly one 16-row tile per wave (churn)

typedef _Float16 half8 __attribute__((ext_vector_type(8)));
typedef _Float16 half4 __attribute__((ext_vector_type(4)));
typedef _Float16 h2v   __attribute__((ext_vector_type(2)));
typedef float    f32x4 __attribute__((ext_vector_type(4)));
typedef float    f32x2 __attribute__((ext_vector_type(2)));

// ---- fp8 e4m3 (OCP) helpers ----
static __device__ __forceinline__ unsigned char ftofp8(float f) {
#if __has_builtin(__builtin_amdgcn_cvt_pk_fp8_f32)
    int r = __builtin_amdgcn_cvt_pk_fp8_f32(f, f, 0, false);
    return (unsigned char)(r & 0xff);
#else
    __hip_fp8_e4m3 v(f);
    unsigned char b; __builtin_memcpy(&b, &v, 1); return b;
#endif
}

// pack 4 floats into 4 fp8 bytes of one u32 (2 instrs)
static __device__ __forceinline__ unsigned int pk4fp8(float a, float b, float c, float d) {
#if __has_builtin(__builtin_amdgcn_cvt_pk_fp8_f32)
    int w = __builtin_amdgcn_cvt_pk_fp8_f32(a, b, 0, false);
    w = __builtin_amdgcn_cvt_pk_fp8_f32(c, d, w, true);
    return (unsigned int)w;
#else
    return (unsigned int)ftofp8(a) | ((unsigned int)ftofp8(b) << 8) |
           ((unsigned int)ftofp8(c) << 16) | ((unsigned int)ftofp8(d) << 24);
#endif
}

template <bool HI>
static __device__ __forceinline__ f32x2 fp8x2tof(unsigned int u) {
#if __has_builtin(__builtin_amdgcn_cvt_pk_f32_fp8)
    return __builtin_amdgcn_cvt_pk_f32_fp8(u, HI);  // HI is a constant here
#else
    f32x2 r;
    #pragma unroll
    for (int i = 0; i < 2; i++) {
        unsigned char b = (u >> (8 * (i + (HI ? 2 : 0)))) & 0xff;
        __hip_fp8_e4m3 v; __builtin_memcpy(&v, &b, 1); r[i] = (float)v;
    }
    return r;
#endif
}

// packed f16 relu
static __device__ __forceinline__ half8 h8_relu(half8 v) {
    half8 z = {};
#if __has_builtin(__builtin_elementwise_max)
    return __builtin_elementwise_max(v, z);
#else
    half8 o;
    #pragma unroll
    for (int i = 0; i < 8; i++) o[i] = v[i] > (_Float16)0 ? v[i] : (_Float16)0;
    return o;
#endif
}

// ---------------- CSR pass 1 (blocks 0..195): bin edges into 391 dst buckets ----------------
// blocks 196..388: W -> Wt (transposed f16, permuted rows) + gstart binary search (merged prepw3)
__global__ __launch_bounds__(256) void k_bucket1(const int* __restrict__ src,
                                                 const int* __restrict__ dst,
                                                 int* __restrict__ bcnt,
                                                 unsigned int* __restrict__ staging,
                                                 const float* __restrict__ W0,
                                                 const float* __restrict__ W1,
                                                 const float* __restrict__ W2,
                                                 _Float16* __restrict__ Wt,
                                                 const int* __restrict__ batch,
                                                 int* __restrict__ gstart) {
    int tid = threadIdx.x;
    if (blockIdx.x >= B1B) {
        int pb = blockIdx.x - B1B;          // 0..192
        if (pb == 192) {
            int g = tid;
            if (g > NG) return;
            if (g == NG) { gstart[g] = NN; return; }
            int lo = 0, hi = NN;
            while (lo < hi) { int mid = (lo + hi) >> 1; if (batch[mid] < g) lo = mid + 1; else hi = mid; }
            gstart[g] = lo;
            return;
        }
        int gi = pb * 256 + tid;            // 3 * 16384
        int l = gi >> 14, idx = gi & 16383;
        const float* W = (l == 0) ? W0 : (l == 1) ? W1 : W2;
        int n = idx >> 7, k = idx & 127;
        int c = ((n & 15) << 3) | (n >> 4);
        Wt[gi - idx + (n << 7) + k] = (_Float16)W[k * 128 + c];
        return;
    }
    __shared__ int hist[NB];
    __shared__ int base[NB];
    int chunk0 = blockIdx.x * 8192;
    bool full = (chunk0 + 8192 <= NE);
    for (int i = tid; i < NB; i += 256) hist[i] = 0;
    __syncthreads();
    if (full) {
        for (int i = tid * 4; i < 8192; i += 1024) {
            int4 d4 = *(const int4*)&dst[chunk0 + i];
            atomicAdd(&hist[d4.x >> 8], 1);
            atomicAdd(&hist[d4.y >> 8], 1);
            atomicAdd(&hist[d4.z >> 8], 1);
            atomicAdd(&hist[d4.w >> 8], 1);
        }
    } else {
        for (int i = tid; i < 8192; i += 256) {
            int e = chunk0 + i;
            if (e < NE) atomicAdd(&hist[dst[e] >> 8], 1);
        }
    }
    __syncthreads();
    for (int i = tid; i < NB; i += 256) {
        base[i] = atomicAdd(&bcnt[i], hist[i]);
        hist[i] = 0;
    }
    __syncthreads();
    if (full) {
        for (int i = tid * 4; i < 8192; i += 1024) {
            int4 d4 = *(const int4*)&dst[chunk0 + i];
            int4 s4 = *(const int4*)&src[chunk0 + i];
            #pragma unroll
            for (int k = 0; k < 4; k++) {
                int d = (k == 0) ? d4.x : (k == 1) ? d4.y : (k == 2) ? d4.z : d4.w;
                int s = (k == 0) ? s4.x : (k == 1) ? s4.y : (k == 2) ? s4.z : s4.w;
                int bk = d >> 8;
                int off = base[bk] + atomicAdd(&hist[bk], 1);
                if (off < CAP)
                    staging[(size_t)bk * CAP + off] = ((unsigned)s << 8) | (unsigned)(d & 255);
            }
        }
    } else {
        for (int i = tid; i < 8192; i += 256) {
            int e = chunk0 + i;
            if (e < NE) {
                int d = dst[e];
                int bk = d >> 8;
                int off = base[bk] + atomicAdd(&hist[bk], 1);
                if (off < CAP)
                    staging[(size_t)bk * CAP + off] = ((unsigned)src[e] << 8) | (unsigned)(d & 255);
            }
        }
    }
}

// ---------------- CSR pass 2: 391 blocks, 256 nodes/block, 1 node/thread; uint4 scans ----------------
__global__ __launch_bounds__(256) void k_bucket2(const unsigned int* __restrict__ staging,
                                                 const int* __restrict__ bcnt,
                                                 int* __restrict__ rowptr,
                                                 float* __restrict__ dis,
                                                 int* __restrict__ col) {
    __shared__ int degl[256];
    __shared__ int cur[256];
    __shared__ int tsum[256];
    __shared__ int sbc[NB];
    __shared__ int sbase_s;
    int b = blockIdx.x, tid = threadIdx.x;
    for (int i = tid; i < NB; i += 256) sbc[i] = bcnt[i];
    degl[tid] = 0;
    __syncthreads();
    if (tid == 0) { int r = 0; for (int i = 0; i < b; i++) r += sbc[i]; sbase_s = r; }
    __syncthreads();
    int cnt = sbc[b]; if (cnt > CAP) cnt = CAP;
    int base = sbase_s;
    const unsigned int* st = staging + (size_t)b * CAP;
    int nv = cnt & ~3;   // vectorizable prefix (bucket base is 16B-aligned)
    for (int i = tid * 4; i < nv; i += 1024) {
        uint4 e4 = *(const uint4*)&st[i];
        atomicAdd(&degl[e4.x & 255], 1);
        atomicAdd(&degl[e4.y & 255], 1);
        atomicAdd(&degl[e4.z & 255], 1);
        atomicAdd(&degl[e4.w & 255], 1);
    }
    for (int i = nv + tid; i < cnt; i += 256) atomicAdd(&degl[st[i] & 255], 1);
    __syncthreads();
    int d = degl[tid];
    tsum[tid] = d;
    __syncthreads();
    for (int off = 1; off < 256; off <<= 1) {
        int t = (tid >= off) ? tsum[tid - off] : 0;
        __syncthreads();
        tsum[tid] += t;
        __syncthreads();
    }
    int excl = tsum[tid] - d;
    int node = b * 256 + tid;
    if (node <= NN) rowptr[node] = base + excl;
    if (node < NN) {
        cur[tid] = excl;
        dis[node] = rsqrtf((float)d + 1.0f);
    }
    __syncthreads();
    for (int i = tid * 4; i < nv; i += 1024) {
        uint4 e4 = *(const uint4*)&st[i];
        #pragma unroll
        for (int k = 0; k < 4; k++) {
            unsigned int e = (k == 0) ? e4.x : (k == 1) ? e4.y : (k == 2) ? e4.z : e4.w;
            int pos = atomicAdd(&cur[e & 255], 1);
            col[base + pos] = (int)(e >> 8);
        }
    }
    for (int i = nv + tid; i < cnt; i += 256) {
        unsigned int e = st[i];
        int pos = atomicAdd(&cur[e & 255], 1);
        col[base + pos] = (int)(e >> 8);
    }
}

// ---------------- MFMA GEMM v5 (reverted from v6): persistent W in LDS, one tile/wave ----------------
// Round-10 lesson: per-wave direct L2 reads of W regressed +23us/dispatch -- block-shared
// LDS staging amortizes operand latency across the block; keep it.
__global__ __launch_bounds__(256) void k_gemm(const float* __restrict__ Xf,
                                              const _Float16* __restrict__ Xh,
                                              const float* __restrict__ sp,
                                              const float* __restrict__ gamma,
                                              const float* __restrict__ beta,
                                              const _Float16* __restrict__ Wt,
                                              const float* __restrict__ dis,
                                              unsigned char* __restrict__ Y) {
    __shared__ _Float16 Wl[128][136];
    __shared__ _Float16 ssh[256];
    __shared__ float sums[256];
    int tid = threadIdx.x;
    #pragma unroll
    for (int p = 0; p < 8; p++) {
        int idx = p * 2048 + tid * 8;
        int r = idx >> 7, c = idx & 127;
        *(uint4*)&Wl[r][c] = ((const uint4*)Wt)[idx >> 3];
    }
    if (Xh) {
        float a = 0.f;
        #pragma unroll 4
        for (int i = 0; i < NSLOT; i++) a += sp[i * 256 + tid];
        sums[tid] = a;
        __syncthreads();
        if (tid < 128) {
            float mean = sums[tid] * (1.0f / NN);
            float var  = sums[128 + tid] * (1.0f / NN) - mean * mean;
            float sc   = gamma[tid] * rsqrtf(var + 1e-5f);
            ssh[tid] = (_Float16)sc;
            ssh[128 + tid] = (_Float16)(beta[tid] - mean * sc);
        }
    }
    __syncthreads();

    int lane = tid & 63;
    int m = lane & 15;
    int quad = lane >> 4;
    const int NT = (NN + 15) / 16;          // 6250 tiles

    int t = blockIdx.x * 4 + (tid >> 6);    // one tile per wave
    if (t < NT) {
        int row = t * 16 + m;
        bool ok = row < NN;
        half8 afrag[4];
        if (Xh) {
            #pragma unroll
            for (int kc = 0; kc < 4; kc++) {
                int k0 = kc * 32 + quad * 8;
                half8 hv = {};
                if (ok) hv = *(const half8*)&Xh[(size_t)row * H + k0];
                half8 scv = *(const half8*)&ssh[k0];
                half8 shv = *(const half8*)&ssh[k0 + 128];
                afrag[kc] = h8_relu(hv * scv + shv);
            }
        } else {
            #pragma unroll
            for (int kc = 0; kc < 4; kc++) {
                int k0 = kc * 32 + quad * 8;
                float4 v0 = make_float4(0.f, 0.f, 0.f, 0.f);
                float4 v1 = make_float4(0.f, 0.f, 0.f, 0.f);
                if (ok) {
                    v0 = *(const float4*)&Xf[(size_t)row * H + k0];
                    v1 = *(const float4*)&Xf[(size_t)row * H + k0 + 4];
                }
                half8 o = {(_Float16)v0.x, (_Float16)v0.y, (_Float16)v0.z, (_Float16)v0.w,
                           (_Float16)v1.x, (_Float16)v1.y, (_Float16)v1.z, (_Float16)v1.w};
                afrag[kc] = o;
            }
        }

        f32x4 acc[8];
        #pragma unroll
        for (int nt = 0; nt < 8; nt++) acc[nt] = (f32x4){0.f, 0.f, 0.f, 0.f};
        #pragma unroll
        for (int kc = 0; kc < 4; kc++) {
            #pragma unroll
            for (int nt = 0; nt < 8; nt++) {
                half8 b = *(const half8*)&Wl[nt * 16 + m][kc * 32 + quad * 8];
                acc[nt] = __builtin_amdgcn_mfma_f32_16x16x32_f16(afrag[kc], b, acc[nt], 0, 0, 0);
            }
        }

        #pragma unroll
        for (int r = 0; r < 4; r++) {
            int gr = t * 16 + quad * 4 + r;
            if (gr < NN) {
                float dv = dis[gr];
                unsigned int lo = pk4fp8(acc[0][r] * dv, acc[1][r] * dv,
                                         acc[2][r] * dv, acc[3][r] * dv);
                unsigned int hi = pk4fp8(acc[4][r] * dv, acc[5][r] * dv,
                                         acc[6][r] * dv, acc[7][r] * dv);
                uint2 pk = make_uint2(lo, hi);
                *(uint2*)&Y[(size_t)gr * H + m * 8] = pk;
            }
        }
    }
}

// ---------------- gather aggregate + BN stats partials ----------------
// Round-0-proven latency structure: ONE node per wave, short-lived waves, 8 edge
// substreams x 8 feature-lanes, uint4 gathers, 2-deep unroll (16 outstanding loads).
// Epilogue: reduce-scatter butterfly, LDS flush + 256 sp atomics per 4-node block.
// NO device fence (round-3: per-block __threadfence = 34x regression).
// NSLOT=128: ~8 concurrent atomic writers per sp address (32 caused +5us, round 7).
__global__ __launch_bounds__(256) void k_agg(const unsigned char* __restrict__ hs,
                                             const int* __restrict__ rowptr,
                                             const int* __restrict__ col,
                                             const float* __restrict__ dis,
                                             const float* __restrict__ bias,
                                             _Float16* __restrict__ out,
                                             float* __restrict__ sp) {
    int wv = threadIdx.x >> 6;            // 0..3
    int lane = threadIdx.x & 63;
    int fl = lane & 7;     // feature slice: feats 16*fl .. 16*fl+15
    int sub = lane >> 3;   // edge sub-stream 0..7
    int b0 = sub & 1, b1 = (sub >> 1) & 1, b2 = (sub >> 2) & 1;
    const uint4* h16 = (const uint4*)hs;  // 8 uint4 per 128B row
    int node = blockIdx.x * 4 + wv;       // grid exactly covers NN
    int beg = rowptr[node], end = rowptr[node + 1];
    float dd = dis[node];
    // after reduce-scatter this lane owns feature pair p = fl*16 + sub*2
    float2 bb = *(const float2*)&bias[fl * 16 + sub * 2];

    f32x2 acc2[8];
    #pragma unroll
    for (int k = 0; k < 8; k++) acc2[k] = (f32x2){0.f, 0.f};

    #define ACCUM(W) { \
        acc2[0] += fp8x2tof<false>((W).x); acc2[1] += fp8x2tof<true>((W).x); \
        acc2[2] += fp8x2tof<false>((W).y); acc2[3] += fp8x2tof<true>((W).y); \
        acc2[4] += fp8x2tof<false>((W).z); acc2[5] += fp8x2tof<true>((W).z); \
        acc2[6] += fp8x2tof<false>((W).w); acc2[7] += fp8x2tof<true>((W).w); }
    #define SHFL2(d, s, m) { (d)[0] = __shfl_xor((s)[0], (m), 64); (d)[1] = __shfl_xor((s)[1], (m), 64); }

    if (sub == 0) {                               // self-loop term
        uint4 w = h16[(size_t)node * 8 + fl];
        ACCUM(w)
    }
    int j = beg + sub;
    for (; j + 8 < end; j += 16) {
        int c0 = col[j], c1 = col[j + 8];
        uint4 w0 = h16[(size_t)c0 * 8 + fl];
        uint4 w1 = h16[(size_t)c1 * 8 + fl];
        ACCUM(w0) ACCUM(w1)
    }
    for (; j < end; j += 8) {
        uint4 w = h16[(size_t)col[j] * 8 + fl];
        ACCUM(w)
    }
    #undef ACCUM

    // ---- reduce-scatter butterfly: lane (fl,sub) ends with sum for pair t = sub ----
    f32x2 n0, n1, n2, n3, t, r;
    t = b0 ? acc2[0] : acc2[1]; SHFL2(r, t, 8); n0 = (b0 ? acc2[1] : acc2[0]) + r;
    t = b0 ? acc2[2] : acc2[3]; SHFL2(r, t, 8); n1 = (b0 ? acc2[3] : acc2[2]) + r;
    t = b0 ? acc2[4] : acc2[5]; SHFL2(r, t, 8); n2 = (b0 ? acc2[5] : acc2[4]) + r;
    t = b0 ? acc2[6] : acc2[7]; SHFL2(r, t, 8); n3 = (b0 ? acc2[7] : acc2[6]) + r;
    f32x2 m0, m1;
    t = b1 ? n0 : n1; SHFL2(r, t, 16); m0 = (b1 ? n1 : n0) + r;
    t = b1 ? n2 : n3; SHFL2(r, t, 16); m1 = (b1 ? n3 : n2) + r;
    t = b2 ? m0 : m1; SHFL2(r, t, 32); f32x2 fin = (b2 ? m1 : m0) + r;
    #undef SHFL2

    float o0 = fin[0] * dd + bb.x;
    float o1 = fin[1] * dd + bb.y;
    h2v ov = { (_Float16)o0, (_Float16)o1 };
    *(h2v*)&out[(size_t)node * H + fl * 16 + sub * 2] = ov;   // coalesced 256B row / wave

    __shared__ float lsum[4][128];
    __shared__ float lsq[4][128];
    {
        int p = fl * 16 + sub * 2;
        *(float2*)&lsum[wv][p] = make_float2(o0, o1);
        *(float2*)&lsq[wv][p]  = make_float2(o0 * o0, o1 * o1);
    }
    __syncthreads();
    int c = threadIdx.x & 127;
    int which = threadIdx.x >> 7;  // 0 = sum, 1 = sumsq
    float v = 0.f;
    #pragma unroll
    for (int w = 0; w < 4; w++) v += which ? lsq[w][c] : lsum[w][c];
    atomicAdd(&sp[(blockIdx.x & (NSLOT - 1)) * 256 + which * 128 + c], v);
}

// ---------------- fused BN-stats reduce + mean pool (BN+ReLU) + MLP head + log_softmax ----------------
__global__ __launch_bounds__(1024) void k_poolhead(const _Float16* __restrict__ x,
                                                   const float* __restrict__ sp,
                                                   const float* __restrict__ gamma,
                                                   const float* __restrict__ beta,
                                                   const int* __restrict__ gstart,
                                                   const float* __restrict__ w1, const float* __restrict__ b1,
                                                   const float* __restrict__ w2, const float* __restrict__ b2,
                                                   float* __restrict__ out) {
    __shared__ float part[4][256];
    __shared__ float ssl[256];
    int t = threadIdx.x;
    {
        int c = t & 255, g4 = t >> 8;     // 4 groups x NSLOT/4 slots
        float a = 0.f;
        for (int i = g4 * (NSLOT / 4); i < (g4 + 1) * (NSLOT / 4); i++) a += sp[i * 256 + c];
        part[g4][c] = a;
    }
    __syncthreads();
    if (t < 256) part[0][t] = part[0][t] + part[1][t] + part[2][t] + part[3][t];
    __syncthreads();
    if (t < 128) {
        float mean = part[0][t] * (1.0f / NN);
        float var  = part[0][128 + t] * (1.0f / NN) - mean * mean;
        float sc   = gamma[t] * rsqrtf(var + 1e-5f);
        ssl[t] = sc;
        ssl[128 + t] = beta[t] - mean * sc;
    }
    __syncthreads();

    int g = blockIdx.x;
    int beg = gstart[g], end = gstart[g + 1];
    int lane = t & 31;
    int walker = t >> 5;   // 0..31
    const half4* x4 = (const half4*)x;
    float4 sc4 = ((const float4*)ssl)[lane];
    float4 sh4 = ((const float4*)(ssl + 128))[lane];
    float4 acc = make_float4(0.f, 0.f, 0.f, 0.f);
    for (int r = beg + walker; r < end; r += 32) {
        half4 v = x4[(size_t)r * 32 + lane];
        acc.x += fmaxf((float)v.x * sc4.x + sh4.x, 0.f);
        acc.y += fmaxf((float)v.y * sc4.y + sh4.y, 0.f);
        acc.z += fmaxf((float)v.z * sc4.z + sh4.z, 0.f);
        acc.w += fmaxf((float)v.w * sc4.w + sh4.w, 0.f);
    }
    __shared__ float4 red[1024];
    __shared__ float p[H], hh[H], lg[NC], lsred;
    red[t] = acc;
    __syncthreads();
    if (t < 32) {
        float4 s = red[t];
        for (int w = 1; w < 32; w++) {
            float4 v = red[w * 32 + t];
            s.x += v.x; s.y += v.y; s.z += v.z; s.w += v.w;
        }
        float inv = 1.0f / fmaxf((float)(end - beg), 1.0f);
        ((float4*)p)[t] = make_float4(s.x * inv, s.y * inv, s.z * inv, s.w * inv);
    }
    __syncthreads();
    int f = t;
    if (f < H) {
        float a = b1[f];
        for (int k = 0; k < H; k++) a += p[k] * w1[k * H + f];
        hh[f] = a > 0.f ? a : 0.f;
    }
    __syncthreads();
    if (f < NC) {
        float l = b2[f];
        for (int k = 0; k < H; k++) l += hh[k] * w2[k * NC + f];
        lg[f] = l;
    }
    __syncthreads();
    if (f == 0) {
        float m = lg[0];
        for (int c = 1; c < NC; c++) m = m > lg[c] ? m : lg[c];
        float s = 0.f;
        for (int c = 0; c < NC; c++) s += expf(lg[c] - m);
        lsred = m + logf(s);
    }
    __syncthreads();
    if (f < NC) out[g * NC + f] = lg[f] - lsred;
}

extern "C" void kernel_launch(void* const* d_in, const int* in_sizes, int n_in,
                              void* d_out, int out_size, void* d_ws, size_t ws_size,
                              hipStream_t stream) {
    const float* x     = (const float*)d_in[0];
    const int*   ei    = (const int*)d_in[1];
    const int*   srcp  = ei;
    const int*   dstp  = ei + NE;
    const int*   batch = (const int*)d_in[2];
    const float* W[3]  = {(const float*)d_in[3],  (const float*)d_in[7],  (const float*)d_in[11]};
    const float* b[3]  = {(const float*)d_in[4],  (const float*)d_in[8],  (const float*)d_in[12]};
    const float* gm[3] = {(const float*)d_in[5],  (const float*)d_in[9],  (const float*)d_in[13]};
    const float* bt[3] = {(const float*)d_in[6],  (const float*)d_in[10], (const float*)d_in[14]};
    const float* w1 = (const float*)d_in[15];
    const float* b1 = (const float*)d_in[16];
    const float* w2 = (const float*)d_in[17];
    const float* b2 = (const float*)d_in[18];
    float* out = (float*)d_out;

    float* ws        = (float*)d_ws;
    float* dis       = ws;                          // 100000
    int*   rowptr    = (int*)(ws + 100000);         // 100001 (pad 100004)
    int*   gstart    = (int*)(ws + 200004);         // 101 (pad 104)
    int*   bcnt      = (int*)(ws + 200108);         // 391 (pad 512)
    float* sp        = ws + 200620;                 // 3 layers x NSLOT*256 = 98304
    _Float16* wt     = (_Float16*)(ws + 298924);    // 3*16384 halves = 24576 floats
    int*   col       = (int*)(ws + 323500);         // NE
    unsigned int* staging = (unsigned int*)(ws + 1923500);  // NB*CAP = 1801728
    _Float16* aggh   = (_Float16*)(ws + 3725228);   // NN*H f16 = 6400000 floats
    unsigned char* hb = (unsigned char*)(ws + 10125228);  // NN*H fp8

    // one memset covers bcnt (512) + all 3 layers' sp partials
    (void)hipMemsetAsync(bcnt, 0, (512 + 3 * NSLOT * 256) * sizeof(float), stream);
    k_bucket1<<<B1B + 193, 256, 0, stream>>>(srcp, dstp, bcnt, staging,
                                             W[0], W[1], W[2], wt, batch, gstart);
    k_bucket2<<<NB, 256, 0, stream>>>(staging, bcnt, rowptr, dis, col);

    for (int l = 0; l < 3; l++) {
        k_gemm<<<GEMM_BLOCKS, 256, 0, stream>>>(
            l == 0 ? x : nullptr,
            l == 0 ? nullptr : aggh,
            l == 0 ? nullptr : sp + (l - 1) * NSLOT * 256,
            l == 0 ? nullptr : gm[l - 1],
            l == 0 ? nullptr : bt[l - 1],
            wt + l * 16384, dis, hb);
        k_agg<<<NN / 4, 256, 0, stream>>>(hb, rowptr, col, dis, b[l], aggh,
                                          sp + l * NSLOT * 256);
    }

    k_poolhead<<<NG, 1024, 0, stream>>>(aggh, sp + 2 * NSLOT * 256, gm[2], bt[2],
                                        gstart, w1, b1, w2, b2, out);
}